// Round 5
// baseline (211.306 us; speedup 1.0000x reference)
//
#include <hip/hip_runtime.h>
#include <hip/hip_bf16.h>

#define K 128
#define NB 4096
#define EPB 8                  // examples per block
#define FW_ITERS 50

// ---------- DPP cross-lane helpers (proven in rounds 3-4, absmax 0.0) ----------
template<int CTRL>
__device__ __forceinline__ float dpp_fmin(float v) {
    int s = __builtin_amdgcn_update_dpp(__float_as_int(v), __float_as_int(v), CTRL, 0xF, 0xF, false);
    return fminf(v, __int_as_float(s));
}
template<int CTRL>
__device__ __forceinline__ float dpp_fadd(float v) {
    int s = __builtin_amdgcn_update_dpp(__float_as_int(v), __float_as_int(v), CTRL, 0xF, 0xF, false);
    return v + __int_as_float(s);
}

__device__ __forceinline__ float wave_fmin_all(float v) {
    v = dpp_fmin<0xB1>(v);   // quad_perm xor1
    v = dpp_fmin<0x4E>(v);   // quad_perm xor2
    v = dpp_fmin<0x124>(v);  // row_ror:4
    v = dpp_fmin<0x128>(v);  // row_ror:8 -> per-16 min
#if __has_builtin(__builtin_amdgcn_permlane16_swap)
    {
        auto r = __builtin_amdgcn_permlane16_swap(__float_as_int(v), __float_as_int(v), false, false);
        v = fminf(__int_as_float(r[0]), __int_as_float(r[1]));
    }
#else
    v = fminf(v, __shfl_xor(v, 16, 64));
#endif
#if __has_builtin(__builtin_amdgcn_permlane32_swap)
    {
        auto r = __builtin_amdgcn_permlane32_swap(__float_as_int(v), __float_as_int(v), false, false);
        v = fminf(__int_as_float(r[0]), __int_as_float(r[1]));
    }
#else
    v = fminf(v, __shfl_xor(v, 32, 64));
#endif
    return v;
}

// per-32-lane-half sum (lanes 0-31 and 32-63 independently), result in all lanes
__device__ __forceinline__ float half_sum32(float v) {
    v = dpp_fadd<0xB1>(v);
    v = dpp_fadd<0x4E>(v);
    v = dpp_fadd<0x124>(v);
    v = dpp_fadd<0x128>(v);
#if __has_builtin(__builtin_amdgcn_permlane16_swap)
    {
        auto r = __builtin_amdgcn_permlane16_swap(__float_as_int(v), __float_as_int(v), false, false);
        v = __int_as_float(r[0]) + __int_as_float(r[1]);
    }
#else
    v = v + __shfl_xor(v, 16, 64);
#endif
    return v;
}

__device__ __forceinline__ unsigned short bf16_bits(float f) {
    __hip_bfloat16 h = __float2bfloat16(f);
    return *reinterpret_cast<unsigned short*>(&h);
}

// XOR swizzle for the pair-packed M layout: word(r, col) = col*64 + (r ^ swz(col)),
// word holds bf16 of rows (2r, 2r+1) at column col. Conflict-free for build stores,
// FW column gather, and val column reads (<=2 lanes/bank everywhere).
__device__ __forceinline__ int swz(int col) {
    return ((col >> 2) + ((col & 3) << 3)) & 31;
}

// ---------- intra-block producer/consumer sync (LDS monotone counters) ----------
__device__ __forceinline__ void spin_ge(int* f, int tgt) {
    while (*(volatile int*)f < tgt) __builtin_amdgcn_s_sleep(1);
    asm volatile("" ::: "memory");
}
// release: drain LDS stores of this wave, then one atomic increment.
// (LDS-only waitcnt: must NOT wait vmcnt, or prefetched global loads would serialize.)
__device__ __forceinline__ void release_inc(int* f, int lane) {
    asm volatile("s_waitcnt lgkmcnt(0)" ::: "memory");
    if (lane == 0) atomicAdd(f, 1);
}

__global__ __launch_bounds__(256, 2) void cacis_main(
    const float* __restrict__ scores,
    const float* __restrict__ C,
    const int* __restrict__ targets,
    float* __restrict__ out_partial)
{
    __shared__ unsigned int Mw[2][K * 64];   // 2 x 32 KB, swizzled pair-packed bf16
    __shared__ float s_l[2][K];
    __shared__ float grow[2][K];
    __shared__ float alpha_l[2][K];
    __shared__ float pred[2][2][3];          // [parity][producer wave][sumC,trace,minv]
    __shared__ float eps_a[2], minv_a[2];
    __shared__ int   flg[8];                 // s_cnt[2], red_cnt[2], built_cnt[2], free_cnt[2]

    const int b   = blockIdx.x;
    const int tid = threadIdx.x;
    const int w   = tid >> 6;
    const int lane = tid & 63;

    if (tid < 8) flg[tid] = 0;
    __syncthreads();   // the ONLY all-wave barrier; roles diverge after this

    if (w >= 2) {
        // ================= producers (waves 2,3): load + reduce + build M =================
        const int pt = tid - 128;            // 0..127
        const int wv = w - 2;                // 0 or 1
        const int cb = 4 * (pt & 31);        // column base
        const int rh = pt >> 5;              // 0..3: row offset within each 4-row group
        float4 c[32];
        float sreg;
        {
            const float* Cb = C + (size_t)(b * EPB) * (K * K);
            #pragma unroll
            for (int j = 0; j < 32; ++j)
                c[j] = *reinterpret_cast<const float4*>(Cb + 4 * pt + 512 * j);
            sreg = scores[(b * EPB) * K + pt];
        }

        for (int e = 0; e < EPB; ++e) {
            const int ex = b * EPB + e;
            const int p = e & 1, u = e >> 1;

            spin_ge(&flg[6 + p], u);         // buffer p free (consumer done with use u-1)
            s_l[p][pt] = sreg;
            release_inc(&flg[0 + p], lane);  // scores staged
            spin_ge(&flg[0 + p], 2 * (u + 1));

            // ---- pass 1: t = s_i + s_j + C; partials sumC / trace / min ----
            float4 s4 = *reinterpret_cast<const float4*>(&s_l[p][cb]);
            float sumC = 0.f, trace = 0.f, minv = 1e30f;
            #pragma unroll
            for (int j = 0; j < 32; ++j) {
                const int row = 4 * j + rh;
                const float sr = s_l[p][row];
                float4 v = c[j];
                sumC += (v.x + v.y) + (v.z + v.w);
                const int d = row - cb;
                if (d >= 0 && d < 4)
                    trace += (d == 0) ? v.x : (d == 1) ? v.y : (d == 2) ? v.z : v.w;
                v.x = sr + s4.x + v.x;
                v.y = sr + s4.y + v.y;
                v.z = sr + s4.z + v.z;
                v.w = sr + s4.w + v.w;
                c[j] = v;
                minv = fminf(minv, fminf(fminf(v.x, v.y), fminf(v.z, v.w)));
            }
            #pragma unroll
            for (int m = 1; m < 64; m <<= 1) {
                sumC  += __shfl_xor(sumC, m, 64);
                trace += __shfl_xor(trace, m, 64);
                minv   = fminf(minv, __shfl_xor(minv, m, 64));
            }
            if (lane == 0) { pred[p][wv][0] = sumC; pred[p][wv][1] = trace; pred[p][wv][2] = minv; }
            release_inc(&flg[2 + p], lane);
            spin_ge(&flg[2 + p], 2 * (u + 1));
            sumC  = pred[p][0][0] + pred[p][1][0];
            trace = pred[p][0][1] + pred[p][1][1];
            minv  = fminf(pred[p][0][2], pred[p][1][2]);

            float eps = fmaxf((sumC - trace) * (1.0f / (float)(K * (K - 1))), 1e-8f);
            const float inv_eps = 1.0f / eps;
            if (wv == 0 && lane == 0) { eps_a[p] = eps; minv_a[p] = minv; }

            // ---- pass 2: M = exp((minv-t)/eps) -> swizzled bf16 LDS + fp32 rowsums;
            //      next example's C loads reuse c[j] right after consumption ----
            const float* Cb_n = C + (size_t)(ex + 1) * (K * K);
            #pragma unroll
            for (int j = 0; j < 32; ++j) {
                const int row = 4 * j + rh;
                float4 t = c[j];
                float m0 = __expf((minv - t.x) * inv_eps);
                float m1 = __expf((minv - t.y) * inv_eps);
                float m2 = __expf((minv - t.z) * inv_eps);
                float m3 = __expf((minv - t.w) * inv_eps);
                const int r = row >> 1, hh = row & 1;
                ((unsigned short*)&Mw[p][((cb + 0) << 6) + (r ^ swz(cb + 0))])[hh] = bf16_bits(m0);
                ((unsigned short*)&Mw[p][((cb + 1) << 6) + (r ^ swz(cb + 1))])[hh] = bf16_bits(m1);
                ((unsigned short*)&Mw[p][((cb + 2) << 6) + (r ^ swz(cb + 2))])[hh] = bf16_bits(m2);
                ((unsigned short*)&Mw[p][((cb + 3) << 6) + (r ^ swz(cb + 3))])[hh] = bf16_bits(m3);
                float rs = half_sum32((m0 + m1) + (m2 + m3));   // lanes 0-31 own full row
                if ((lane & 31) == 0) grow[p][row] = rs * (1.0f / (float)K);
                if (e + 1 < EPB)
                    c[j] = *reinterpret_cast<const float4*>(Cb_n + 4 * pt + 512 * j);
            }
            release_inc(&flg[4 + p], lane);  // M(e) built
            if (e + 1 < EPB) sreg = scores[(ex + 1) * K + pt];
        }
    } else {
        // ================= consumers (waves 0,1): FW + val + output =================
        // wave w handles examples e = w, w+2, ... using buffer parity p = w.
        const int l = lane;
        const int p = w;
        for (int u = 0; u < EPB / 2; ++u) {
            const int e = 2 * u + w;
            const int ex = b * EPB + e;
            const int tgt = targets[ex];                  // issue early
            spin_ge(&flg[4 + p], 2 * (u + 1));            // M built
            const float eps  = eps_a[p];
            const float minv = minv_a[p];
            const float f_y  = s_l[p][tgt];

            // Frank-Wolfe, h' = (1-step)h + step*M[:,idx]; it=0 step=1 resets FP state
            float g0 = grow[p][2 * l], g1 = grow[p][2 * l + 1];
            float a0 = 1.0f / K, a1 = 1.0f / K;
            #pragma unroll 1
            for (int it = 0; it < FW_ITERS; ++it) {
                const float v = wave_fmin_all(fminf(g0, g1));
                unsigned long long b0 = __ballot(g0 == v);
                unsigned long long b1 = __ballot(g1 == v);
                int i0 = b0 ? 2 * (int)__builtin_ctzll(b0)     : 0x7fffffff;
                int i1 = b1 ? 2 * (int)__builtin_ctzll(b1) + 1 : 0x7fffffff;
                const int idx = min(i0, i1);              // first-index tie-break

                const float step = 2.0f / (float)(it + 2);
                const float om = 1.0f - step;
                a0 *= om; a1 *= om;
                if (2 * l == idx)     a0 += step;
                if (2 * l + 1 == idx) a1 += step;
                // one conflict-free b32: bf16 M[2l][idx] (lo) and M[2l+1][idx] (hi)
                unsigned uw = Mw[p][(idx << 6) + (l ^ swz(idx))];
                g0 = om * g0 + step * __uint_as_float(uw << 16);
                g1 = om * g1 + step * __uint_as_float(uw & 0xffff0000u);
            }
            alpha_l[p][2 * l]     = a0;
            alpha_l[p][2 * l + 1] = a1;

            // val = alpha^T M alpha (lane l owns columns 2l, 2l+1)
            const int c0 = 2 * l, c1 = 2 * l + 1;
            const int b0i = c0 << 6, s0 = swz(c0);
            const int b1i = c1 << 6, s1 = swz(c1);
            float acc0 = 0.f, acc1 = 0.f;
            #pragma unroll
            for (int r = 0; r < 64; ++r) {
                unsigned u0 = Mw[p][b0i + (r ^ s0)];
                unsigned u1 = Mw[p][b1i + (r ^ s1)];
                float2 ap = *reinterpret_cast<float2*>(&alpha_l[p][2 * r]);   // broadcast
                acc0 += ap.x * __uint_as_float(u0 << 16) + ap.y * __uint_as_float(u0 & 0xffff0000u);
                acc1 += ap.x * __uint_as_float(u1 << 16) + ap.y * __uint_as_float(u1 & 0xffff0000u);
            }
            float valp = a0 * acc0 + a1 * acc1;
            #pragma unroll
            for (int m = 1; m < 64; m <<= 1) valp += __shfl_xor(valp, m, 64);
            if (l == 0) {
                // conjugate = -eps*(log(val+1e-12) + shift), shift = -minv/eps
                out_partial[ex] = -eps * logf(valp + 1e-12f) + minv - f_y;
            }
            release_inc(&flg[6 + p], l);     // buffer p free for use u+1
        }
    }
}

__global__ __launch_bounds__(256) void cacis_reduce(
    const float* __restrict__ part, float* __restrict__ out)
{
    __shared__ float red[4];
    const int tid = threadIdx.x;
    float acc = 0.f;
    for (int i = tid; i < NB; i += 256) acc += part[i];
    #pragma unroll
    for (int m = 1; m < 64; m <<= 1) acc += __shfl_xor(acc, m, 64);
    if ((tid & 63) == 0) red[tid >> 6] = acc;
    __syncthreads();
    if (tid == 0) out[0] = ((red[0] + red[1]) + (red[2] + red[3])) * (1.0f / (float)NB);
}

extern "C" void kernel_launch(void* const* d_in, const int* in_sizes, int n_in,
                              void* d_out, int out_size, void* d_ws, size_t ws_size,
                              hipStream_t stream) {
    const float* scores  = (const float*)d_in[0];
    const float* C       = (const float*)d_in[1];
    const int*   targets = (const int*)d_in[2];
    float* out  = (float*)d_out;
    float* part = (float*)d_ws;   // NB floats = 16 KB

    cacis_main<<<NB / EPB, 256, 0, stream>>>(scores, C, targets, part);
    cacis_reduce<<<1, 256, 0, stream>>>(part, out);
}

// Round 6
// 97.318 us; speedup vs baseline: 2.1713x; 2.1713x over previous
//
#include <hip/hip_runtime.h>
#include <hip/hip_bf16.h>

#define K 128
#define NB 4096
#define FW_ITERS 50

// ---------- DPP cross-lane helpers (validated rounds 3-5, absmax 0.0) ----------
template<int CTRL>
__device__ __forceinline__ float dpp_fmin(float v) {
    int s = __builtin_amdgcn_update_dpp(__float_as_int(v), __float_as_int(v), CTRL, 0xF, 0xF, false);
    return fminf(v, __int_as_float(s));
}
template<int CTRL>
__device__ __forceinline__ float dpp_fadd(float v) {
    int s = __builtin_amdgcn_update_dpp(__float_as_int(v), __float_as_int(v), CTRL, 0xF, 0xF, false);
    return v + __int_as_float(s);
}

__device__ __forceinline__ float wave_fmin_all(float v) {
    v = dpp_fmin<0xB1>(v);   // quad_perm xor1
    v = dpp_fmin<0x4E>(v);   // quad_perm xor2
    v = dpp_fmin<0x124>(v);  // row_ror:4
    v = dpp_fmin<0x128>(v);  // row_ror:8 -> per-16 min
#if __has_builtin(__builtin_amdgcn_permlane16_swap)
    {
        auto r = __builtin_amdgcn_permlane16_swap(__float_as_int(v), __float_as_int(v), false, false);
        v = fminf(__int_as_float(r[0]), __int_as_float(r[1]));
    }
#else
    v = fminf(v, __shfl_xor(v, 16, 64));
#endif
#if __has_builtin(__builtin_amdgcn_permlane32_swap)
    {
        auto r = __builtin_amdgcn_permlane32_swap(__float_as_int(v), __float_as_int(v), false, false);
        v = fminf(__int_as_float(r[0]), __int_as_float(r[1]));
    }
#else
    v = fminf(v, __shfl_xor(v, 32, 64));
#endif
    return v;
}

// per-32-lane-half sum (lanes 0-31 / 32-63 independently), result in all lanes
__device__ __forceinline__ float half_sum32(float v) {
    v = dpp_fadd<0xB1>(v);
    v = dpp_fadd<0x4E>(v);
    v = dpp_fadd<0x124>(v);
    v = dpp_fadd<0x128>(v);
#if __has_builtin(__builtin_amdgcn_permlane16_swap)
    {
        auto r = __builtin_amdgcn_permlane16_swap(__float_as_int(v), __float_as_int(v), false, false);
        v = __int_as_float(r[0]) + __int_as_float(r[1]);
    }
#else
    v = v + __shfl_xor(v, 16, 64);
#endif
    return v;
}

__device__ __forceinline__ unsigned short bf16_bits(float f) {
    __hip_bfloat16 h = __float2bfloat16(f);
    return *reinterpret_cast<unsigned short*>(&h);
}

// XOR swizzle: word(r, col) = col*64 + (r ^ swz(col)); word = bf16 rows (2r,2r+1) at col.
// Build stores, FW column gather, val column reads: all <=2 lanes/bank (0 conflicts, r5).
__device__ __forceinline__ int swz(int col) {
    return ((col >> 2) + ((col & 3) << 3)) & 31;
}

__global__ __launch_bounds__(256, 4) void cacis_main(
    const float* __restrict__ scores,
    const float* __restrict__ C,
    const int* __restrict__ targets,
    float* __restrict__ out_partial)
{
    __shared__ unsigned int Mw[K * 64];        // 32 KB swizzled pair-packed bf16
    __shared__ __align__(16) float s_lds[K];
    __shared__ __align__(16) float grow[K];
    __shared__ __align__(16) float alpha[K];
    __shared__ float red[4][4];

    const int b = blockIdx.x;
    const int tid = threadIdx.x;
    const int w = tid >> 6;
    const int lane = tid & 63;

    // ---- anti-convoy stagger: first generation only (b < 1024); co-resident
    // blocks {i, i+256, i+512, i+768} get offsets 0/1/2/3 x ~3.4us ----
    if (b < 1024) {
        const int stag = (b >> 8) & 3;
        for (int i = 0; i < stag * 4; ++i) __builtin_amdgcn_s_sleep(32);  // 32*64 cy each
    }

    if (tid < K) s_lds[tid] = scores[b * K + tid];
    __syncthreads();

    // Thread t owns float4 chunks: row_j = 8*j + (t>>5), cols [4*(t&31), +4) -> coalesced
    const float* Cb = C + (size_t)b * (K * K);
    const int cb = 4 * (tid & 31);
    float4 c[16];
    float sc[4];
    {
        float4 s4 = *reinterpret_cast<const float4*>(&s_lds[cb]);
        sc[0] = s4.x; sc[1] = s4.y; sc[2] = s4.z; sc[3] = s4.w;
    }

    #pragma unroll
    for (int j = 0; j < 16; ++j)
        c[j] = *reinterpret_cast<const float4*>(Cb + 4 * tid + 1024 * j);

    float sumC = 0.f, trace = 0.f, minv = 1e30f;
    #pragma unroll
    for (int j = 0; j < 16; ++j) {
        const int row = 8 * j + (tid >> 5);
        const float sr = s_lds[row];
        float4 v = c[j];
        sumC += (v.x + v.y) + (v.z + v.w);
        const int d = row - cb;
        if (d >= 0 && d < 4)
            trace += (d == 0) ? v.x : (d == 1) ? v.y : (d == 2) ? v.z : v.w;
        float t0 = sr + sc[0] + v.x;
        float t1 = sr + sc[1] + v.y;
        float t2 = sr + sc[2] + v.z;
        float t3 = sr + sc[3] + v.w;
        c[j] = make_float4(t0, t1, t2, t3);
        minv = fminf(minv, fminf(fminf(t0, t1), fminf(t2, t3)));
    }

    // block reduce (sumC, trace, minv)
    #pragma unroll
    for (int m = 1; m < 64; m <<= 1) {
        sumC  += __shfl_xor(sumC, m, 64);
        trace += __shfl_xor(trace, m, 64);
        minv   = fminf(minv, __shfl_xor(minv, m, 64));
    }
    if (lane == 0) { red[w][0] = sumC; red[w][1] = trace; red[w][2] = minv; }
    __syncthreads();
    sumC  = (red[0][0] + red[1][0]) + (red[2][0] + red[3][0]);
    trace = (red[0][1] + red[1][1]) + (red[2][1] + red[3][1]);
    minv  = fminf(fminf(red[0][2], red[1][2]), fminf(red[2][2], red[3][2]));

    float eps = fmaxf((sumC - trace) * (1.0f / (float)(K * (K - 1))), 1e-8f);  // EPS_SCALE=1
    const float inv_eps = 1.0f / eps;

    // M = exp((minv - t)/eps): swizzled bf16 to LDS + fused fp32 rowsum (r5-validated)
    // Within wave w: lanes 0-31 own full row 8j+2w, lanes 32-63 own row 8j+2w+1.
    #pragma unroll
    for (int j = 0; j < 16; ++j) {
        const int row = 8 * j + (tid >> 5);
        float4 t = c[j];
        float m0 = __expf((minv - t.x) * inv_eps);
        float m1 = __expf((minv - t.y) * inv_eps);
        float m2 = __expf((minv - t.z) * inv_eps);
        float m3 = __expf((minv - t.w) * inv_eps);
        const int r = row >> 1, hh = row & 1;
        ((unsigned short*)&Mw[((cb + 0) << 6) + (r ^ swz(cb + 0))])[hh] = bf16_bits(m0);
        ((unsigned short*)&Mw[((cb + 1) << 6) + (r ^ swz(cb + 1))])[hh] = bf16_bits(m1);
        ((unsigned short*)&Mw[((cb + 2) << 6) + (r ^ swz(cb + 2))])[hh] = bf16_bits(m2);
        ((unsigned short*)&Mw[((cb + 3) << 6) + (r ^ swz(cb + 3))])[hh] = bf16_bits(m3);
        float rs = half_sum32((m0 + m1) + (m2 + m3));
        if ((lane & 31) == 0) grow[row] = rs * (1.0f / (float)K);   // h_0 = rowsum/K
    }
    __syncthreads();

    // ---- Frank-Wolfe: wave 0 only; h' = (1-step)h + step*M[:,idx] (it=0 step=1 resets FP) ----
    if (w == 0) {
        const int l = lane;
        float g0 = grow[2 * l], g1 = grow[2 * l + 1];
        float a0 = 1.0f / K, a1 = 1.0f / K;
        #pragma unroll 1
        for (int it = 0; it < FW_ITERS; ++it) {
            const float v = wave_fmin_all(fminf(g0, g1));
            unsigned long long b0 = __ballot(g0 == v);
            unsigned long long b1 = __ballot(g1 == v);
            int i0 = b0 ? 2 * (int)__builtin_ctzll(b0)     : 0x7fffffff;
            int i1 = b1 ? 2 * (int)__builtin_ctzll(b1) + 1 : 0x7fffffff;
            const int idx = min(i0, i1);              // first-index tie-break

            const float step = 2.0f / (float)(it + 2);
            const float om = 1.0f - step;
            a0 *= om; a1 *= om;
            if (2 * l == idx)     a0 += step;
            if (2 * l + 1 == idx) a1 += step;
            // one conflict-free b32: bf16 M[2l][idx] (lo half) and M[2l+1][idx] (hi half)
            unsigned uw = Mw[(idx << 6) + (l ^ swz(idx))];
            g0 = om * g0 + step * __uint_as_float(uw << 16);
            g1 = om * g1 + step * __uint_as_float(uw & 0xffff0000u);
        }
        alpha[2 * l]     = a0;
        alpha[2 * l + 1] = a1;
    }
    __syncthreads();

    // ---- val = alpha^T M alpha, parallel over 256 threads (col-owner, r4-validated) ----
    {
        const int col = tid >> 1, rh = tid & 1;
        const int cb6 = col << 6, sw = swz(col);
        const float ac = alpha[col];
        float acc = 0.f;
        #pragma unroll
        for (int k = 0; k < 32; ++k) {
            const int r = rh * 32 + k;
            unsigned u = Mw[cb6 + (r ^ sw)];
            float2 ap = *reinterpret_cast<const float2*>(&alpha[2 * r]);
            acc += ap.x * __uint_as_float(u << 16) + ap.y * __uint_as_float(u & 0xffff0000u);
        }
        float valp = acc * ac;
        #pragma unroll
        for (int m = 1; m < 64; m <<= 1) valp += __shfl_xor(valp, m, 64);
        if (lane == 0) red[w][0] = valp;
    }
    __syncthreads();
    if (tid == 0) {
        const float val = (red[0][0] + red[1][0]) + (red[2][0] + red[3][0]);
        // conjugate = -eps*(log(val+1e-12) + shift), shift = -minv/eps -> -eps*log(..) + minv
        const float conj = -eps * logf(val + 1e-12f) + minv;
        const int tgt = targets[b];
        out_partial[b] = conj - s_lds[tgt];
    }
}

__global__ __launch_bounds__(256) void cacis_reduce(
    const float* __restrict__ part, float* __restrict__ out)
{
    __shared__ float red[4];
    const int tid = threadIdx.x;
    float acc = 0.f;
    for (int i = tid; i < NB; i += 256) acc += part[i];
    #pragma unroll
    for (int m = 1; m < 64; m <<= 1) acc += __shfl_xor(acc, m, 64);
    if ((tid & 63) == 0) red[tid >> 6] = acc;
    __syncthreads();
    if (tid == 0) out[0] = ((red[0] + red[1]) + (red[2] + red[3])) * (1.0f / (float)NB);
}

extern "C" void kernel_launch(void* const* d_in, const int* in_sizes, int n_in,
                              void* d_out, int out_size, void* d_ws, size_t ws_size,
                              hipStream_t stream) {
    const float* scores  = (const float*)d_in[0];
    const float* C       = (const float*)d_in[1];
    const int*   targets = (const int*)d_in[2];
    float* out  = (float*)d_out;
    float* part = (float*)d_ws;   // NB floats = 16 KB

    cacis_main<<<NB, 256, 0, stream>>>(scores, C, targets, part);
    cacis_reduce<<<1, 256, 0, stream>>>(part, out);
}